// Round 1
// baseline (1051.161 us; speedup 1.0000x reference)
//
#include <hip/hip_runtime.h>
#include <hip/hip_bf16.h>
#include <math.h>

// Problem constants
#define QN 300
#define BN 2
#define SN 4096
#define DN 256
#define HN 8
#define HD 32
#define BH 16
#define DFF 2048

// ---------------- wave helpers (wave = 64) ----------------
__device__ inline float wred_max(float v) {
#pragma unroll
    for (int m = 32; m > 0; m >>= 1) v = fmaxf(v, __shfl_xor(v, m));
    return v;
}
__device__ inline float wred_sum(float v) {
#pragma unroll
    for (int m = 32; m > 0; m >>= 1) v += __shfl_xor(v, m);
    return v;
}

// ---------------- add + layernorm ----------------
// out_ln = LN(a+b)*g+be ; optionally also write raw sum
__global__ __launch_bounds__(256) void addln_kernel(
    const float* __restrict__ a, const float* __restrict__ b,
    const float* __restrict__ g, const float* __restrict__ be,
    float* __restrict__ out_ln, float* __restrict__ out_sum)
{
    int row = blockIdx.x;
    int t = threadIdx.x;
    float v = a[row * DN + t] + b[row * DN + t];
    if (out_sum) out_sum[row * DN + t] = v;
    float s = wred_sum(v);
    float s2 = wred_sum(v * v);
    __shared__ float ws1[4], ws2[4];
    int wave = t >> 6, lane = t & 63;
    if (lane == 0) { ws1[wave] = s; ws2[wave] = s2; }
    __syncthreads();
    float S1 = ws1[0] + ws1[1] + ws1[2] + ws1[3];
    float S2 = ws2[0] + ws2[1] + ws2[2] + ws2[3];
    float mean = S1 * (1.0f / DN);
    float var = S2 * (1.0f / DN) - mean * mean;
    float inv = rsqrtf(var + 1e-5f);
    out_ln[row * DN + t] = (v - mean) * inv * g[t] + be[t];
}

// ---------------- elementwise add (float4) ----------------
__global__ void addvec_kernel(const float* __restrict__ a, const float* __restrict__ b,
                              float* __restrict__ c, int n4)
{
    int i = blockIdx.x * blockDim.x + threadIdx.x;
    int stride = gridDim.x * blockDim.x;
    for (; i < n4; i += stride) {
        float4 x = ((const float4*)a)[i];
        float4 y = ((const float4*)b)[i];
        float4 z; z.x = x.x + y.x; z.y = x.y + y.y; z.z = x.z + y.z; z.w = x.w + y.w;
        ((float4*)c)[i] = z;
    }
}

// ---------------- xq = x1+query_pos ; xo = x1+masked(query_pos) ----------------
__global__ __launch_bounds__(256) void build_xq_xo(
    const float* __restrict__ x1, const float* __restrict__ qp,
    const int* __restrict__ ro1, const int* __restrict__ ro2,
    float* __restrict__ xq, float* __restrict__ xo)
{
    int row = blockIdx.x, t = threadIdx.x;
    int q = row >> 1, b = row & 1;
    const int* ro = b ? ro2 : ro1;
    bool msk = (ro[q * 4 + 0] == 0) || (ro[q * 4 + 1] == 0) ||
               (ro[q * 4 + 2] == 0) || (ro[q * 4 + 3] == 0);
    float xv = x1[row * DN + t], qv = qp[row * DN + t];
    xq[row * DN + t] = xv + qv;
    xo[row * DN + t] = xv + (msk ? 0.0f : qv);
}

// ---------------- generic GEMM: C = act((A @ W^T + bias) * scale) ----------------
// A [M,K] row-major, W [N,K] row-major. MODE 0: plain, 1: relu, 2: head-layout
// head layout: m -> (b=m&1, seq=m>>1); n -> (h=n>>5, hd=n&31);
//   C[((b*8+h)*seqLen + seq)*32 + hd]
template <int MODE>
__global__ __launch_bounds__(256) void gemm_nt(
    const float* __restrict__ A, const float* __restrict__ W,
    const float* __restrict__ bias, float* __restrict__ C,
    int M, int N, int K, int seqLen, float scale)
{
    __shared__ float As[16][68];
    __shared__ float Bs[16][68];
    int bm = blockIdx.x * 64;
    int bn = blockIdx.y * 64;
    int t = threadIdx.x;
    int lr = t >> 2;           // 0..63
    int lc = (t & 3) << 2;     // 0,4,8,12
    int tm = (t >> 4) << 2;    // 0..60
    int tn = (t & 15) << 2;    // 0..60
    float acc[4][4] = {};
    for (int k0 = 0; k0 < K; k0 += 16) {
        int arow = bm + lr;
        float4 av = make_float4(0, 0, 0, 0);
        if (arow < M) av = *(const float4*)&A[(size_t)arow * K + k0 + lc];
        float4 bv = *(const float4*)&W[(size_t)(bn + lr) * K + k0 + lc];
        __syncthreads();
        As[lc + 0][lr] = av.x; As[lc + 1][lr] = av.y; As[lc + 2][lr] = av.z; As[lc + 3][lr] = av.w;
        Bs[lc + 0][lr] = bv.x; Bs[lc + 1][lr] = bv.y; Bs[lc + 2][lr] = bv.z; Bs[lc + 3][lr] = bv.w;
        __syncthreads();
#pragma unroll
        for (int kk = 0; kk < 16; kk++) {
            float4 a = *(const float4*)&As[kk][tm];
            float4 b = *(const float4*)&Bs[kk][tn];
            acc[0][0] = fmaf(a.x, b.x, acc[0][0]); acc[0][1] = fmaf(a.x, b.y, acc[0][1]);
            acc[0][2] = fmaf(a.x, b.z, acc[0][2]); acc[0][3] = fmaf(a.x, b.w, acc[0][3]);
            acc[1][0] = fmaf(a.y, b.x, acc[1][0]); acc[1][1] = fmaf(a.y, b.y, acc[1][1]);
            acc[1][2] = fmaf(a.y, b.z, acc[1][2]); acc[1][3] = fmaf(a.y, b.w, acc[1][3]);
            acc[2][0] = fmaf(a.z, b.x, acc[2][0]); acc[2][1] = fmaf(a.z, b.y, acc[2][1]);
            acc[2][2] = fmaf(a.z, b.z, acc[2][2]); acc[2][3] = fmaf(a.z, b.w, acc[2][3]);
            acc[3][0] = fmaf(a.w, b.x, acc[3][0]); acc[3][1] = fmaf(a.w, b.y, acc[3][1]);
            acc[3][2] = fmaf(a.w, b.z, acc[3][2]); acc[3][3] = fmaf(a.w, b.w, acc[3][3]);
        }
    }
#pragma unroll
    for (int i = 0; i < 4; i++) {
        int m = bm + tm + i;
        if (m >= M) continue;
#pragma unroll
        for (int j = 0; j < 4; j++) {
            int n = bn + tn + j;
            float v = acc[i][j] + bias[n];
            if (MODE == 1) v = fmaxf(v, 0.0f);
            if (MODE == 2) {
                v *= scale;
                int b = m & 1, seq = m >> 1, h = n >> 5, hd = n & 31;
                C[((size_t)(b * 8 + h) * seqLen + seq) * 32 + hd] = v;
            } else {
                C[(size_t)m * N + n] = v;
            }
        }
    }
}

// ---------------- small heads: p2 / p3 / p1_W2 + ref/point/scale assembly ----------------
__global__ __launch_bounds__(64) void small_heads(
    const float* __restrict__ ln4, const float* __restrict__ h2,
    const float* __restrict__ p2W, const float* __restrict__ p2b,
    const float* __restrict__ p3W, const float* __restrict__ p3b,
    const float* __restrict__ p1W2, const float* __restrict__ p1b2,
    const float* __restrict__ h_w,
    float* __restrict__ ref_inter_out, float* __restrict__ ref_out,
    float* __restrict__ point, float* __restrict__ scale2)
{
    int row = blockIdx.x;       // q*2+b
    int lane = threadIdx.x;     // 64
    __shared__ float rA[DN], rH[DN];
    __shared__ float po[16], sc[16], ri[2];
#pragma unroll
    for (int i = 0; i < 4; i++) {
        rA[lane + i * 64] = ln4[row * DN + lane + i * 64];
        rH[lane + i * 64] = h2[row * DN + lane + i * 64];
    }
    __syncthreads();
    for (int j = 0; j < 16; j++) {
        float p = 0;
#pragma unroll
        for (int i = 0; i < 4; i++) { int d = lane + i * 64; p = fmaf(rA[d], p2W[j * DN + d], p); }
        p = wred_sum(p);
        if (lane == 0) po[j] = p + p2b[j];
    }
    for (int j = 0; j < 16; j++) {
        float p = 0;
#pragma unroll
        for (int i = 0; i < 4; i++) { int d = lane + i * 64; p = fmaf(rA[d], p3W[j * DN + d], p); }
        p = wred_sum(p);
        if (lane == 0) sc[j] = p + p3b[j];
    }
    for (int j = 0; j < 2; j++) {
        float p = 0;
#pragma unroll
        for (int i = 0; i < 4; i++) { int d = lane + i * 64; p = fmaf(rH[d], p1W2[j * DN + d], p); }
        p = wred_sum(p);
        if (lane == 0) ri[j] = p + p1b2[j];
    }
    __syncthreads();
    int q = row >> 1, b = row & 1;
    float sig0 = 1.0f / (1.0f + expf(-ri[0]));
    float sig1 = 1.0f / (1.0f + expf(-ri[1]));
    float rx = h_w[b * 2 + 0] * sig0 * (1.0f / 32.0f);
    float ry = h_w[b * 2 + 1] * sig1 * (1.0f / 32.0f);
    if (lane < 2) ref_inter_out[row * 2 + lane] = ri[lane];
    if (lane < 16) {
        float rc = (lane & 1) ? ry : rx;
        ref_out[row * 16 + lane] = rc;
        int pidx = (q * 16 + b * 8 + (lane >> 1)) * 2 + (lane & 1);
        point[pidx] = rc + po[lane];
        float s = sc[lane];
        scale2[pidx] = s * s;
    }
}

// ---------------- fused flash attention (fp32), optional Gaussian bias ----------------
// qp/kp/vp layout: [bh][seq][32]. out layout: [q][b][h*32+d] (=[L,B,D] flat).
// bias(bh,q,s) = -(sx*(px-gx)^2 + sy*(py-gy)^2)/8 from point/scale2 [Q][16][2], grid [S][2].
template <bool BIAS>
__global__ __launch_bounds__(256) void attn_kernel(
    const float* __restrict__ qp, const float* __restrict__ kp, const float* __restrict__ vp,
    const float* __restrict__ point, const float* __restrict__ scale2,
    const float* __restrict__ grid_xy,
    float* __restrict__ outbuf, int S, int L)
{
    const int bh = blockIdx.y;
    const int q0 = blockIdx.x * 16;
    __shared__ float Qs[16][36];
    __shared__ float Ks[64][36];
    __shared__ float Vsf[64 * 32];
    __shared__ float Ps[16][68];
    __shared__ float sf_s[16], l_s[16];
    __shared__ float pt_s[16][2], sc_s[16][2];

    int t = threadIdx.x;
    int wave = t >> 6, lane = t & 63;

    { // stage Q tile
        int qi = t >> 4, d = (t & 15) * 2;
        int gq = q0 + qi;
        float2 v = make_float2(0, 0);
        if (gq < L) v = *(const float2*)&qp[((size_t)bh * L + gq) * 32 + d];
        Qs[qi][d] = v.x; Qs[qi][d + 1] = v.y;
        if (BIAS && t < 32) {
            int qi2 = t >> 1, c = t & 1;
            int gq2 = q0 + qi2;
            pt_s[qi2][c] = (gq2 < L) ? point[(gq2 * 16 + bh) * 2 + c] : 0.0f;
            sc_s[qi2][c] = (gq2 < L) ? scale2[(gq2 * 16 + bh) * 2 + c] : 0.0f;
        }
    }
    float m_run[4], l_run[4];
#pragma unroll
    for (int r = 0; r < 4; r++) { m_run[r] = -INFINITY; l_run[r] = 0.0f; }
    int pq = t >> 4, pd = t & 15;
    float2 acc = make_float2(0.0f, 0.0f);
    __syncthreads();

    for (int s0 = 0; s0 < S; s0 += 64) {
        // stage K and V tiles
#pragma unroll
        for (int rep = 0; rep < 2; rep++) {
            int f = t + rep * 256;      // float4 id 0..511
            int s = f >> 3, dc = (f & 7) * 4;
            int gs = s0 + s;
            float4 kv = make_float4(0, 0, 0, 0), vv = make_float4(0, 0, 0, 0);
            if (gs < S) {
                kv = *(const float4*)&kp[((size_t)bh * S + gs) * 32 + dc];
                vv = *(const float4*)&vp[((size_t)bh * S + gs) * 32 + dc];
            }
            Ks[s][dc + 0] = kv.x; Ks[s][dc + 1] = kv.y; Ks[s][dc + 2] = kv.z; Ks[s][dc + 3] = kv.w;
            Vsf[s * 32 + dc + 0] = vv.x; Vsf[s * 32 + dc + 1] = vv.y;
            Vsf[s * 32 + dc + 2] = vv.z; Vsf[s * 32 + dc + 3] = vv.w;
        }
        float gx = 0, gy = 0;
        if (BIAS) {
            int gs = s0 + lane;
            if (gs < S) { gx = grid_xy[gs * 2 + 0]; gy = grid_xy[gs * 2 + 1]; }
        }
        __syncthreads();

        // ---- logits + online softmax: wave w handles q rows w*4..w*4+3, lane = s
        float kreg[32];
#pragma unroll
        for (int d4 = 0; d4 < 8; d4++) {
            float4 kk = *(const float4*)&Ks[lane][d4 * 4];
            kreg[d4 * 4 + 0] = kk.x; kreg[d4 * 4 + 1] = kk.y;
            kreg[d4 * 4 + 2] = kk.z; kreg[d4 * 4 + 3] = kk.w;
        }
        bool svalid = (s0 + lane) < S;
#pragma unroll
        for (int r = 0; r < 4; r++) {
            int qi = wave * 4 + r;
            float sum = 0;
#pragma unroll
            for (int d4 = 0; d4 < 8; d4++) {
                float4 qv = *(const float4*)&Qs[qi][d4 * 4];
                sum = fmaf(qv.x, kreg[d4 * 4 + 0], sum);
                sum = fmaf(qv.y, kreg[d4 * 4 + 1], sum);
                sum = fmaf(qv.z, kreg[d4 * 4 + 2], sum);
                sum = fmaf(qv.w, kreg[d4 * 4 + 3], sum);
            }
            if (BIAS) {
                float dx = pt_s[qi][0] - gx, dy = pt_s[qi][1] - gy;
                sum -= (sc_s[qi][0] * dx * dx + sc_s[qi][1] * dy * dy) * 0.125f;
            }
            float l = svalid ? sum : -INFINITY;
            float tmax = wred_max(l);
            float m_new = fmaxf(m_run[r], tmax);
            float p = expf(l - m_new);
            float psum = wred_sum(p);
            float sfv = expf(m_run[r] - m_new);
            l_run[r] = l_run[r] * sfv + psum;
            m_run[r] = m_new;
            Ps[qi][lane] = p;
            if (lane == 0) sf_s[qi] = sfv;
        }
        __syncthreads();

        // ---- PV: thread owns (pq, d=2*pd..2*pd+1)
        {
            float sfv = sf_s[pq];
            acc.x *= sfv; acc.y *= sfv;
#pragma unroll
            for (int s4 = 0; s4 < 16; s4++) {
                float4 p4 = *(const float4*)&Ps[pq][s4 * 4];
                float2 v0 = *(const float2*)&Vsf[(s4 * 4 + 0) * 32 + pd * 2];
                float2 v1 = *(const float2*)&Vsf[(s4 * 4 + 1) * 32 + pd * 2];
                float2 v2 = *(const float2*)&Vsf[(s4 * 4 + 2) * 32 + pd * 2];
                float2 v3 = *(const float2*)&Vsf[(s4 * 4 + 3) * 32 + pd * 2];
                acc.x = fmaf(p4.x, v0.x, acc.x); acc.y = fmaf(p4.x, v0.y, acc.y);
                acc.x = fmaf(p4.y, v1.x, acc.x); acc.y = fmaf(p4.y, v1.y, acc.y);
                acc.x = fmaf(p4.z, v2.x, acc.x); acc.y = fmaf(p4.z, v2.y, acc.y);
                acc.x = fmaf(p4.w, v3.x, acc.x); acc.y = fmaf(p4.w, v3.y, acc.y);
            }
        }
        __syncthreads();
    }

    if (lane == 0) {
#pragma unroll
        for (int r = 0; r < 4; r++) l_s[wave * 4 + r] = l_run[r];
    }
    __syncthreads();
    int gq = q0 + pq;
    if (gq < L) {
        float inv = 1.0f / l_s[pq];
        int b = bh >> 3, h = bh & 7;
        float* o = &outbuf[((size_t)gq * BN + b) * DN + h * 32 + pd * 2];
        o[0] = acc.x * inv;
        o[1] = acc.y * inv;
    }
}

// ---------------- launch ----------------
// workspace offsets (floats)
#define OFF_QK      0
#define OFF_LN4     153600
#define OFF_H1      307200
#define OFF_TMP     307200   /* reuses H1 after small_heads */
#define OFF_H2      460800
#define OFF_POINT   614400
#define OFF_SCALE2  624000
#define OFF_SAQ     633600
#define OFF_SAK     787200
#define OFF_SAV     940800
#define OFF_AOUT    1094400
#define OFF_X1      1248000
#define OFF_MP      1401600
#define OFF_CAK     3498752
#define OFF_CAV     5595904
#define OFF_XQ      7693056
#define OFF_XO      7846656
#define OFF_AOUT2   8000256
#define OFF_AOUT3   8153856
#define OFF_X2      8307456
#define OFF_FFH     8461056
// end: 9,689,856 floats (~38.8 MB)

// d_out offsets: x:0, ref_inter:153600, ref:154800, tgt3:164400 (total 318000)

extern "C" void kernel_launch(void* const* d_in, const int* in_sizes, int n_in,
                              void* d_out, int out_size, void* d_ws, size_t ws_size,
                              hipStream_t stream)
{
    const float* grid_in   = (const float*)d_in[0];
    const float* h_w       = (const float*)d_in[1];
    const float* tgt       = (const float*)d_in[2];
    const float* memory    = (const float*)d_in[3];
    const float* pos       = (const float*)d_in[4];
    const float* query_pos = (const float*)d_in[5];
    const int*   ro1       = (const int*)d_in[6];
    const int*   ro2       = (const int*)d_in[7];
    const float* sa_Wi = (const float*)d_in[8];
    const float* sa_bi = (const float*)d_in[9];
    const float* sa_Wo = (const float*)d_in[10];
    const float* sa_bo = (const float*)d_in[11];
    const float* ca_Wi = (const float*)d_in[12];
    const float* ca_bi = (const float*)d_in[13];
    const float* ca_Wo = (const float*)d_in[14];
    const float* ca_bo = (const float*)d_in[15];
    const float* W1 = (const float*)d_in[16];
    const float* b1 = (const float*)d_in[17];
    const float* W2 = (const float*)d_in[18];
    const float* b2 = (const float*)d_in[19];
    const float* n1g = (const float*)d_in[20];
    const float* n1b = (const float*)d_in[21];
    const float* n2g = (const float*)d_in[22];
    const float* n2b = (const float*)d_in[23];
    const float* n3g = (const float*)d_in[24];
    const float* n3b = (const float*)d_in[25];
    const float* n4g = (const float*)d_in[26];
    const float* n4b = (const float*)d_in[27];
    const float* p1_W0 = (const float*)d_in[28];
    const float* p1_b0 = (const float*)d_in[29];
    const float* p1_W1 = (const float*)d_in[30];
    const float* p1_b1 = (const float*)d_in[31];
    const float* p1_W2 = (const float*)d_in[32];
    const float* p1_b2 = (const float*)d_in[33];
    const float* p2W = (const float*)d_in[34];
    const float* p2b = (const float*)d_in[35];
    const float* p3W = (const float*)d_in[36];
    const float* p3b = (const float*)d_in[37];

    float* ws  = (float*)d_ws;
    float* out = (float*)d_out;
    const float qscale = 0.1767766952966369f; // 32^-0.5

    dim3 g600(600), b256(256);
    dim3 gN256(10, 4), gN2048(10, 32), gKV(128, 4);

    // 1. out(ln4) = LN(tgt+query_pos); qk = tgt+query_pos
    addln_kernel<<<g600, b256, 0, stream>>>(tgt, query_pos, n4g, n4b, ws + OFF_LN4, ws + OFF_QK);
    // 2-3. point1 MLP hidden layers
    gemm_nt<1><<<gN256, b256, 0, stream>>>(ws + OFF_LN4, p1_W0, p1_b0, ws + OFF_H1, 600, 256, 256, 0, 1.f);
    gemm_nt<1><<<gN256, b256, 0, stream>>>(ws + OFF_H1, p1_W1, p1_b1, ws + OFF_H2, 600, 256, 256, 0, 1.f);
    // 4. tiny heads + ref/point/scale2 assembly (writes d_out ref_inter + ref)
    small_heads<<<g600, dim3(64), 0, stream>>>(ws + OFF_LN4, ws + OFF_H2, p2W, p2b, p3W, p3b,
                                               p1_W2, p1_b2, h_w,
                                               out + 153600, out + 154800,
                                               ws + OFF_POINT, ws + OFF_SCALE2);
    // 5-7. self-attention projections (head layout [bh][300][32])
    gemm_nt<2><<<gN256, b256, 0, stream>>>(ws + OFF_QK, sa_Wi,          sa_bi,       ws + OFF_SAQ, 600, 256, 256, 300, qscale);
    gemm_nt<2><<<gN256, b256, 0, stream>>>(ws + OFF_QK, sa_Wi + 65536,  sa_bi + 256, ws + OFF_SAK, 600, 256, 256, 300, 1.f);
    gemm_nt<2><<<gN256, b256, 0, stream>>>(tgt,         sa_Wi + 131072, sa_bi + 512, ws + OFF_SAV, 600, 256, 256, 300, 1.f);
    // 8. self-attention
    attn_kernel<false><<<dim3(19, 16), b256, 0, stream>>>(ws + OFF_SAQ, ws + OFF_SAK, ws + OFF_SAV,
                                                          nullptr, nullptr, nullptr,
                                                          ws + OFF_AOUT, 300, 300);
    // 9-10. SA out proj + LN1
    gemm_nt<0><<<gN256, b256, 0, stream>>>(ws + OFF_AOUT, sa_Wo, sa_bo, ws + OFF_TMP, 600, 256, 256, 0, 1.f);
    addln_kernel<<<g600, b256, 0, stream>>>(tgt, ws + OFF_TMP, n1g, n1b, ws + OFF_X1, nullptr);
    // 11. mp = memory + pos
    addvec_kernel<<<dim3(2048), b256, 0, stream>>>(memory, pos, ws + OFF_MP, (SN * BN * DN) / 4);
    // 12-13. CA K/V projections (shared by both passes), head layout [bh][4096][32]
    gemm_nt<2><<<gKV, b256, 0, stream>>>(ws + OFF_MP, ca_Wi + 65536,  ca_bi + 256, ws + OFF_CAK, 8192, 256, 256, 4096, 1.f);
    gemm_nt<2><<<gKV, b256, 0, stream>>>(memory,      ca_Wi + 131072, ca_bi + 512, ws + OFF_CAV, 8192, 256, 256, 4096, 1.f);
    // 14. xq = x1+query_pos ; xo = x1+new_oq
    build_xq_xo<<<g600, b256, 0, stream>>>(ws + OFF_X1, query_pos, ro1, ro2, ws + OFF_XQ, ws + OFF_XO);
    // 15-16. CA Q projections
    gemm_nt<2><<<gN256, b256, 0, stream>>>(ws + OFF_XQ, ca_Wi, ca_bi, ws + OFF_SAQ, 600, 256, 256, 300, qscale);
    gemm_nt<2><<<gN256, b256, 0, stream>>>(ws + OFF_XO, ca_Wi, ca_bi, ws + OFF_SAK, 600, 256, 256, 300, qscale);
    // 17-18. cross attention x2 (with inline Gaussian bias)
    attn_kernel<true><<<dim3(19, 16), b256, 0, stream>>>(ws + OFF_SAQ, ws + OFF_CAK, ws + OFF_CAV,
                                                         ws + OFF_POINT, ws + OFF_SCALE2, grid_in,
                                                         ws + OFF_AOUT2, 4096, 300);
    attn_kernel<true><<<dim3(19, 16), b256, 0, stream>>>(ws + OFF_SAK, ws + OFF_CAK, ws + OFF_CAV,
                                                         ws + OFF_POINT, ws + OFF_SCALE2, grid_in,
                                                         ws + OFF_AOUT3, 4096, 300);
    // 19-20. CA out projections (tgt3 straight to d_out)
    gemm_nt<0><<<gN256, b256, 0, stream>>>(ws + OFF_AOUT2, ca_Wo, ca_bo, ws + OFF_TMP, 600, 256, 256, 0, 1.f);
    gemm_nt<0><<<gN256, b256, 0, stream>>>(ws + OFF_AOUT3, ca_Wo, ca_bo, out + 164400, 600, 256, 256, 0, 1.f);
    // 21. LN2
    addln_kernel<<<g600, b256, 0, stream>>>(ws + OFF_X1, ws + OFF_TMP, n2g, n2b, ws + OFF_X2, nullptr);
    // 22-23. FFN
    gemm_nt<1><<<gN2048, b256, 0, stream>>>(ws + OFF_X2, W1, b1, ws + OFF_FFH, 600, 2048, 256, 0, 1.f);
    gemm_nt<0><<<gN256, b256, 0, stream>>>(ws + OFF_FFH, W2, b2, ws + OFF_TMP, 600, 256, 2048, 0, 1.f);
    // 24. LN3 -> x output
    addln_kernel<<<g600, b256, 0, stream>>>(ws + OFF_X2, ws + OFF_TMP, n3g, n3b, out, nullptr);
}

// Round 2
// 711.670 us; speedup vs baseline: 1.4770x; 1.4770x over previous
//
#include <hip/hip_runtime.h>
#include <hip/hip_bf16.h>
#include <math.h>

// Problem constants
#define QN 300
#define BN 2
#define SN 4096
#define DN 256
#define HN 8
#define HD 32
#define BH 16
#define DFF 2048

// ---------------- wave helpers (wave = 64) ----------------
__device__ inline float wred_max(float v) {
#pragma unroll
    for (int m = 32; m > 0; m >>= 1) v = fmaxf(v, __shfl_xor(v, m));
    return v;
}
__device__ inline float wred_sum(float v) {
#pragma unroll
    for (int m = 32; m > 0; m >>= 1) v += __shfl_xor(v, m);
    return v;
}

// ---------------- add + layernorm ----------------
__global__ __launch_bounds__(256) void addln_kernel(
    const float* __restrict__ a, const float* __restrict__ b,
    const float* __restrict__ g, const float* __restrict__ be,
    float* __restrict__ out_ln, float* __restrict__ out_sum)
{
    int row = blockIdx.x;
    int t = threadIdx.x;
    float v = a[row * DN + t] + b[row * DN + t];
    if (out_sum) out_sum[row * DN + t] = v;
    float s = wred_sum(v);
    float s2 = wred_sum(v * v);
    __shared__ float ws1[4], ws2[4];
    int wave = t >> 6, lane = t & 63;
    if (lane == 0) { ws1[wave] = s; ws2[wave] = s2; }
    __syncthreads();
    float S1 = ws1[0] + ws1[1] + ws1[2] + ws1[3];
    float S2 = ws2[0] + ws2[1] + ws2[2] + ws2[3];
    float mean = S1 * (1.0f / DN);
    float var = S2 * (1.0f / DN) - mean * mean;
    float inv = rsqrtf(var + 1e-5f);
    out_ln[row * DN + t] = (v - mean) * inv * g[t] + be[t];
}

// ---------------- elementwise add (float4) ----------------
__global__ void addvec_kernel(const float* __restrict__ a, const float* __restrict__ b,
                              float* __restrict__ c, int n4)
{
    int i = blockIdx.x * blockDim.x + threadIdx.x;
    int stride = gridDim.x * blockDim.x;
    for (; i < n4; i += stride) {
        float4 x = ((const float4*)a)[i];
        float4 y = ((const float4*)b)[i];
        float4 z; z.x = x.x + y.x; z.y = x.y + y.y; z.z = x.z + y.z; z.w = x.w + y.w;
        ((float4*)c)[i] = z;
    }
}

// ---------------- xq = x1+query_pos ; xo = x1+masked(query_pos) ----------------
__global__ __launch_bounds__(256) void build_xq_xo(
    const float* __restrict__ x1, const float* __restrict__ qp,
    const int* __restrict__ ro1, const int* __restrict__ ro2,
    float* __restrict__ xq, float* __restrict__ xo)
{
    int row = blockIdx.x, t = threadIdx.x;
    int q = row >> 1, b = row & 1;
    const int* ro = b ? ro2 : ro1;
    bool msk = (ro[q * 4 + 0] == 0) || (ro[q * 4 + 1] == 0) ||
               (ro[q * 4 + 2] == 0) || (ro[q * 4 + 3] == 0);
    float xv = x1[row * DN + t], qv = qp[row * DN + t];
    xq[row * DN + t] = xv + qv;
    xo[row * DN + t] = xv + (msk ? 0.0f : qv);
}

// ---------------- big GEMM 64x64 (used for CA K/V projections, M=8192) ----------------
// C = act((A @ W^T + bias) * scale). MODE 0: plain, 1: relu, 2: head-layout
template <int MODE>
__global__ __launch_bounds__(256) void gemm_nt(
    const float* __restrict__ A, const float* __restrict__ W,
    const float* __restrict__ bias, float* __restrict__ C,
    int M, int N, int K, int seqLen, float scale)
{
    __shared__ float As[16][68];
    __shared__ float Bs[16][68];
    int bm = blockIdx.x * 64;
    int bn = blockIdx.y * 64;
    int t = threadIdx.x;
    int lr = t >> 2;
    int lc = (t & 3) << 2;
    int tm = (t >> 4) << 2;
    int tn = (t & 15) << 2;
    float acc[4][4] = {};
    for (int k0 = 0; k0 < K; k0 += 16) {
        int arow = bm + lr;
        float4 av = make_float4(0, 0, 0, 0);
        if (arow < M) av = *(const float4*)&A[(size_t)arow * K + k0 + lc];
        float4 bv = *(const float4*)&W[(size_t)(bn + lr) * K + k0 + lc];
        __syncthreads();
        As[lc + 0][lr] = av.x; As[lc + 1][lr] = av.y; As[lc + 2][lr] = av.z; As[lc + 3][lr] = av.w;
        Bs[lc + 0][lr] = bv.x; Bs[lc + 1][lr] = bv.y; Bs[lc + 2][lr] = bv.z; Bs[lc + 3][lr] = bv.w;
        __syncthreads();
#pragma unroll
        for (int kk = 0; kk < 16; kk++) {
            float4 a = *(const float4*)&As[kk][tm];
            float4 b = *(const float4*)&Bs[kk][tn];
            acc[0][0] = fmaf(a.x, b.x, acc[0][0]); acc[0][1] = fmaf(a.x, b.y, acc[0][1]);
            acc[0][2] = fmaf(a.x, b.z, acc[0][2]); acc[0][3] = fmaf(a.x, b.w, acc[0][3]);
            acc[1][0] = fmaf(a.y, b.x, acc[1][0]); acc[1][1] = fmaf(a.y, b.y, acc[1][1]);
            acc[1][2] = fmaf(a.y, b.z, acc[1][2]); acc[1][3] = fmaf(a.y, b.w, acc[1][3]);
            acc[2][0] = fmaf(a.z, b.x, acc[2][0]); acc[2][1] = fmaf(a.z, b.y, acc[2][1]);
            acc[2][2] = fmaf(a.z, b.z, acc[2][2]); acc[2][3] = fmaf(a.z, b.w, acc[2][3]);
            acc[3][0] = fmaf(a.w, b.x, acc[3][0]); acc[3][1] = fmaf(a.w, b.y, acc[3][1]);
            acc[3][2] = fmaf(a.w, b.z, acc[3][2]); acc[3][3] = fmaf(a.w, b.w, acc[3][3]);
        }
    }
#pragma unroll
    for (int i = 0; i < 4; i++) {
        int m = bm + tm + i;
        if (m >= M) continue;
#pragma unroll
        for (int j = 0; j < 4; j++) {
            int n = bn + tn + j;
            float v = acc[i][j] + bias[n];
            if (MODE == 1) v = fmaxf(v, 0.0f);
            if (MODE == 2) {
                v *= scale;
                int b = m & 1, seq = m >> 1, h = n >> 5, hd = n & 31;
                C[((size_t)(b * 8 + h) * seqLen + seq) * 32 + hd] = v;
            } else {
                C[(size_t)m * N + n] = v;
            }
        }
    }
}

// ---------------- small GEMM 32x32 (for M=600 GEMMs: more blocks) ----------------
template <int MODE>
__global__ __launch_bounds__(256) void gemm_small(
    const float* __restrict__ A, const float* __restrict__ W,
    const float* __restrict__ bias, float* __restrict__ C,
    int M, int N, int K, int seqLen, float scale)
{
    __shared__ float As[16][36];
    __shared__ float Bs[16][36];
    int bm = blockIdx.x * 32;
    int bn = blockIdx.y * 32;
    int t = threadIdx.x;
    int sr = (t & 127) >> 2;   // 0..31
    int sc = (t & 3) << 2;     // 0,4,8,12
    bool isB = t >= 128;
    int tm = (t >> 4) << 1;    // 0..30
    int tn = (t & 15) << 1;    // 0..30
    float acc[2][2] = {};
    int srcRow = (isB ? bn : bm) + sr;
    int lim = isB ? N : M;
    const float* src = isB ? W : A;
    for (int k0 = 0; k0 < K; k0 += 16) {
        float4 v = make_float4(0, 0, 0, 0);
        if (srcRow < lim) v = *(const float4*)&src[(size_t)srcRow * K + k0 + sc];
        __syncthreads();
        float (*Ts)[36] = isB ? Bs : As;
        Ts[sc + 0][sr] = v.x; Ts[sc + 1][sr] = v.y; Ts[sc + 2][sr] = v.z; Ts[sc + 3][sr] = v.w;
        __syncthreads();
#pragma unroll
        for (int kk = 0; kk < 16; kk++) {
            float2 a = *(const float2*)&As[kk][tm];
            float2 b = *(const float2*)&Bs[kk][tn];
            acc[0][0] = fmaf(a.x, b.x, acc[0][0]); acc[0][1] = fmaf(a.x, b.y, acc[0][1]);
            acc[1][0] = fmaf(a.y, b.x, acc[1][0]); acc[1][1] = fmaf(a.y, b.y, acc[1][1]);
        }
    }
#pragma unroll
    for (int i = 0; i < 2; i++) {
        int m = bm + tm + i;
        if (m >= M) continue;
#pragma unroll
        for (int j = 0; j < 2; j++) {
            int n = bn + tn + j;
            float v = acc[i][j] + bias[n];
            if (MODE == 1) v = fmaxf(v, 0.0f);
            if (MODE == 2) {
                v *= scale;
                int b = m & 1, seq = m >> 1, h = n >> 5, hd = n & 31;
                C[((size_t)(b * 8 + h) * seqLen + seq) * 32 + hd] = v;
            } else {
                C[(size_t)m * N + n] = v;
            }
        }
    }
}

// ---------------- small heads: p2 / p3 / p1_W2 + ref/point/scale assembly ----------------
__global__ __launch_bounds__(64) void small_heads(
    const float* __restrict__ ln4, const float* __restrict__ h2,
    const float* __restrict__ p2W, const float* __restrict__ p2b,
    const float* __restrict__ p3W, const float* __restrict__ p3b,
    const float* __restrict__ p1W2, const float* __restrict__ p1b2,
    const float* __restrict__ h_w,
    float* __restrict__ ref_inter_out, float* __restrict__ ref_out,
    float* __restrict__ point, float* __restrict__ scale2)
{
    int row = blockIdx.x;       // q*2+b
    int lane = threadIdx.x;     // 64
    __shared__ float rA[DN], rH[DN];
    __shared__ float po[16], sc[16], ri[2];
#pragma unroll
    for (int i = 0; i < 4; i++) {
        rA[lane + i * 64] = ln4[row * DN + lane + i * 64];
        rH[lane + i * 64] = h2[row * DN + lane + i * 64];
    }
    __syncthreads();
    for (int j = 0; j < 16; j++) {
        float p = 0;
#pragma unroll
        for (int i = 0; i < 4; i++) { int d = lane + i * 64; p = fmaf(rA[d], p2W[j * DN + d], p); }
        p = wred_sum(p);
        if (lane == 0) po[j] = p + p2b[j];
    }
    for (int j = 0; j < 16; j++) {
        float p = 0;
#pragma unroll
        for (int i = 0; i < 4; i++) { int d = lane + i * 64; p = fmaf(rA[d], p3W[j * DN + d], p); }
        p = wred_sum(p);
        if (lane == 0) sc[j] = p + p3b[j];
    }
    for (int j = 0; j < 2; j++) {
        float p = 0;
#pragma unroll
        for (int i = 0; i < 4; i++) { int d = lane + i * 64; p = fmaf(rH[d], p1W2[j * DN + d], p); }
        p = wred_sum(p);
        if (lane == 0) ri[j] = p + p1b2[j];
    }
    __syncthreads();
    int q = row >> 1, b = row & 1;
    float sig0 = 1.0f / (1.0f + expf(-ri[0]));
    float sig1 = 1.0f / (1.0f + expf(-ri[1]));
    float rx = h_w[b * 2 + 0] * sig0 * (1.0f / 32.0f);
    float ry = h_w[b * 2 + 1] * sig1 * (1.0f / 32.0f);
    if (lane < 2) ref_inter_out[row * 2 + lane] = ri[lane];
    if (lane < 16) {
        float rc = (lane & 1) ? ry : rx;
        ref_out[row * 16 + lane] = rc;
        int pidx = (q * 16 + b * 8 + (lane >> 1)) * 2 + (lane & 1);
        point[pidx] = rc + po[lane];
        float s = sc[lane];
        scale2[pidx] = s * s;
    }
}

// ---------------- split flash attention (fp32), S-dim parallel ----------------
// qp/kp/vp layout: [bh][seq][32]. Emits unnormalized partials per chunk:
// pacc [chunk][bh][ROWS][32], pm/pl [chunk][bh][ROWS]
template <bool BIAS>
__global__ __launch_bounds__(256) void attn_split(
    const float* __restrict__ qp, const float* __restrict__ kp, const float* __restrict__ vp,
    const float* __restrict__ point, const float* __restrict__ scale2,
    const float* __restrict__ grid_xy,
    float* __restrict__ pacc, float* __restrict__ pm, float* __restrict__ pl,
    int S, int L, int tilesPerChunk, int ROWS)
{
    const int bh = blockIdx.y;
    const int q0 = blockIdx.x * 16;
    const int chunk = blockIdx.z;
    const int nT = (S + 63) >> 6;
    const int t_begin = chunk * tilesPerChunk;
    const int t_end = min(nT, t_begin + tilesPerChunk);

    __shared__ float Qs[16][36];
    __shared__ float Ks[64][36];
    __shared__ float Vsf[64 * 32];
    __shared__ float Ps[16][68];
    __shared__ float sf_s[16];
    __shared__ float pt_s[16][2], sc_s[16][2];

    int t = threadIdx.x;
    int wave = t >> 6, lane = t & 63;

    { // stage Q tile
        int qi = t >> 4, d = (t & 15) * 2;
        int gq = q0 + qi;
        float2 v = make_float2(0, 0);
        if (gq < L) v = *(const float2*)&qp[((size_t)bh * L + gq) * 32 + d];
        Qs[qi][d] = v.x; Qs[qi][d + 1] = v.y;
        if (BIAS && t < 32) {
            int qi2 = t >> 1, c = t & 1;
            int gq2 = q0 + qi2;
            pt_s[qi2][c] = (gq2 < L) ? point[(gq2 * 16 + bh) * 2 + c] : 0.0f;
            sc_s[qi2][c] = (gq2 < L) ? scale2[(gq2 * 16 + bh) * 2 + c] : 0.0f;
        }
    }
    float m_run[4], l_run[4];
#pragma unroll
    for (int r = 0; r < 4; r++) { m_run[r] = -INFINITY; l_run[r] = 0.0f; }
    int pq = t >> 4, pd = t & 15;
    float2 acc = make_float2(0.0f, 0.0f);
    __syncthreads();

    for (int tt = t_begin; tt < t_end; tt++) {
        int s0 = tt << 6;
#pragma unroll
        for (int rep = 0; rep < 2; rep++) {
            int f = t + rep * 256;
            int s = f >> 3, dc = (f & 7) * 4;
            int gs = s0 + s;
            float4 kv = make_float4(0, 0, 0, 0), vv = make_float4(0, 0, 0, 0);
            if (gs < S) {
                kv = *(const float4*)&kp[((size_t)bh * S + gs) * 32 + dc];
                vv = *(const float4*)&vp[((size_t)bh * S + gs) * 32 + dc];
            }
            Ks[s][dc + 0] = kv.x; Ks[s][dc + 1] = kv.y; Ks[s][dc + 2] = kv.z; Ks[s][dc + 3] = kv.w;
            Vsf[s * 32 + dc + 0] = vv.x; Vsf[s * 32 + dc + 1] = vv.y;
            Vsf[s * 32 + dc + 2] = vv.z; Vsf[s * 32 + dc + 3] = vv.w;
        }
        float gx = 0, gy = 0;
        if (BIAS) {
            int gs = s0 + lane;
            if (gs < S) { gx = grid_xy[gs * 2 + 0]; gy = grid_xy[gs * 2 + 1]; }
        }
        __syncthreads();

        // logits + online softmax: wave w handles q rows w*4..w*4+3, lane = s
        float kreg[32];
#pragma unroll
        for (int d4 = 0; d4 < 8; d4++) {
            float4 kk = *(const float4*)&Ks[lane][d4 * 4];
            kreg[d4 * 4 + 0] = kk.x; kreg[d4 * 4 + 1] = kk.y;
            kreg[d4 * 4 + 2] = kk.z; kreg[d4 * 4 + 3] = kk.w;
        }
        bool svalid = (s0 + lane) < S;
#pragma unroll
        for (int r = 0; r < 4; r++) {
            int qi = wave * 4 + r;
            float sum = 0;
#pragma unroll
            for (int d4 = 0; d4 < 8; d4++) {
                float4 qv = *(const float4*)&Qs[qi][d4 * 4];
                sum = fmaf(qv.x, kreg[d4 * 4 + 0], sum);
                sum = fmaf(qv.y, kreg[d4 * 4 + 1], sum);
                sum = fmaf(qv.z, kreg[d4 * 4 + 2], sum);
                sum = fmaf(qv.w, kreg[d4 * 4 + 3], sum);
            }
            if (BIAS) {
                float dx = pt_s[qi][0] - gx, dy = pt_s[qi][1] - gy;
                sum -= (sc_s[qi][0] * dx * dx + sc_s[qi][1] * dy * dy) * 0.125f;
            }
            float l = svalid ? sum : -INFINITY;
            float tmax = wred_max(l);
            float m_new = fmaxf(m_run[r], tmax);
            float p = expf(l - m_new);
            float psum = wred_sum(p);
            float sfv = expf(m_run[r] - m_new);
            l_run[r] = l_run[r] * sfv + psum;
            m_run[r] = m_new;
            Ps[qi][lane] = p;
            if (lane == 0) sf_s[qi] = sfv;
        }
        __syncthreads();

        // PV: thread owns (pq, d=2*pd..2*pd+1)
        {
            float sfv = sf_s[pq];
            acc.x *= sfv; acc.y *= sfv;
#pragma unroll
            for (int s4 = 0; s4 < 16; s4++) {
                float4 p4 = *(const float4*)&Ps[pq][s4 * 4];
                float2 v0 = *(const float2*)&Vsf[(s4 * 4 + 0) * 32 + pd * 2];
                float2 v1 = *(const float2*)&Vsf[(s4 * 4 + 1) * 32 + pd * 2];
                float2 v2 = *(const float2*)&Vsf[(s4 * 4 + 2) * 32 + pd * 2];
                float2 v3 = *(const float2*)&Vsf[(s4 * 4 + 3) * 32 + pd * 2];
                acc.x = fmaf(p4.x, v0.x, acc.x); acc.y = fmaf(p4.x, v0.y, acc.y);
                acc.x = fmaf(p4.y, v1.x, acc.x); acc.y = fmaf(p4.y, v1.y, acc.y);
                acc.x = fmaf(p4.z, v2.x, acc.x); acc.y = fmaf(p4.z, v2.y, acc.y);
                acc.x = fmaf(p4.w, v3.x, acc.x); acc.y = fmaf(p4.w, v3.y, acc.y);
            }
        }
        __syncthreads();
    }

    // write partials
    if (lane == 0) {
#pragma unroll
        for (int r = 0; r < 4; r++) {
            int row = q0 + wave * 4 + r;
            int pidx = (chunk * 16 + bh) * ROWS + row;
            pm[pidx] = m_run[r];
            pl[pidx] = l_run[r];
        }
    }
    {
        int row = q0 + pq;
        int pidx = (chunk * 16 + bh) * ROWS + row;
        *(float2*)&pacc[(size_t)pidx * 32 + pd * 2] = acc;
    }
}

// ---------------- combine partials: out = sum_c acc_c * e^(m_c-M) / sum_c l_c e^(m_c-M) --------
__global__ __launch_bounds__(256) void attn_combine(
    const float* __restrict__ pacc, const float* __restrict__ pm, const float* __restrict__ pl,
    float* __restrict__ outbuf, int NS, int ROWS, int L)
{
    int gid = blockIdx.x * 256 + threadIdx.x;
    if (gid >= 16 * L * 32) return;
    int d = gid & 31;
    int pr = gid >> 5;
    int bh = pr / L;
    int row = pr - bh * L;
    float M = -INFINITY;
    for (int c = 0; c < NS; c++) M = fmaxf(M, pm[(c * 16 + bh) * ROWS + row]);
    float Lt = 0.0f, a = 0.0f;
    for (int c = 0; c < NS; c++) {
        int pidx = (c * 16 + bh) * ROWS + row;
        float w = expf(pm[pidx] - M);
        Lt = fmaf(pl[pidx], w, Lt);
        a = fmaf(pacc[(size_t)pidx * 32 + d], w, a);
    }
    int b = bh >> 3, h = bh & 7;
    outbuf[((size_t)row * BN + b) * DN + h * 32 + d] = a / Lt;
}

// ---------------- launch ----------------
// workspace offsets (floats)
#define OFF_QK      0
#define OFF_LN4     153600
#define OFF_H1      307200
#define OFF_TMP     307200   /* reuses H1 after small_heads */
#define OFF_H2      460800
#define OFF_POINT   614400
#define OFF_SCALE2  624000
#define OFF_SAQ     633600
#define OFF_SAK     787200
#define OFF_SAV     940800
#define OFF_AOUT    1094400
#define OFF_X1      1248000
#define OFF_MP      1401600
// attention partials overlay MP region (mp dead after CAK gemm; SA partials
// consumed before mp is built). pacc: 8*16*304*32 = 1,245,184 floats.
#define OFF_PACC    1401600
#define OFF_PM      2646784
#define OFF_PL      2685696
#define OFF_CAK     3498752
#define OFF_CAV     5595904
#define OFF_XQ      7693056
#define OFF_XO      7846656
#define OFF_AOUT2   8000256
#define OFF_AOUT3   8153856
#define OFF_X2      8307456
#define OFF_FFH     8461056
// end: 9,689,856 floats (~38.8 MB) — same footprint as round 1

extern "C" void kernel_launch(void* const* d_in, const int* in_sizes, int n_in,
                              void* d_out, int out_size, void* d_ws, size_t ws_size,
                              hipStream_t stream)
{
    const float* grid_in   = (const float*)d_in[0];
    const float* h_w       = (const float*)d_in[1];
    const float* tgt       = (const float*)d_in[2];
    const float* memory    = (const float*)d_in[3];
    const float* pos       = (const float*)d_in[4];
    const float* query_pos = (const float*)d_in[5];
    const int*   ro1       = (const int*)d_in[6];
    const int*   ro2       = (const int*)d_in[7];
    const float* sa_Wi = (const float*)d_in[8];
    const float* sa_bi = (const float*)d_in[9];
    const float* sa_Wo = (const float*)d_in[10];
    const float* sa_bo = (const float*)d_in[11];
    const float* ca_Wi = (const float*)d_in[12];
    const float* ca_bi = (const float*)d_in[13];
    const float* ca_Wo = (const float*)d_in[14];
    const float* ca_bo = (const float*)d_in[15];
    const float* W1 = (const float*)d_in[16];
    const float* b1 = (const float*)d_in[17];
    const float* W2 = (const float*)d_in[18];
    const float* b2 = (const float*)d_in[19];
    const float* n1g = (const float*)d_in[20];
    const float* n1b = (const float*)d_in[21];
    const float* n2g = (const float*)d_in[22];
    const float* n2b = (const float*)d_in[23];
    const float* n3g = (const float*)d_in[24];
    const float* n3b = (const float*)d_in[25];
    const float* n4g = (const float*)d_in[26];
    const float* n4b = (const float*)d_in[27];
    const float* p1_W0 = (const float*)d_in[28];
    const float* p1_b0 = (const float*)d_in[29];
    const float* p1_W1 = (const float*)d_in[30];
    const float* p1_b1 = (const float*)d_in[31];
    const float* p1_W2 = (const float*)d_in[32];
    const float* p1_b2 = (const float*)d_in[33];
    const float* p2W = (const float*)d_in[34];
    const float* p2b = (const float*)d_in[35];
    const float* p3W = (const float*)d_in[36];
    const float* p3b = (const float*)d_in[37];

    float* ws  = (float*)d_ws;
    float* out = (float*)d_out;
    const float qscale = 0.1767766952966369f; // 32^-0.5

    dim3 g600(600), b256(256);
    dim3 gS(19, 8);          // 32x32 tiles for M=600, N=256
    dim3 gFF1(19, 64);       // M=600, N=2048
    dim3 gKV(128, 4);        // 64x64 tiles for M=8192, N=256

    // 1. out(ln4) = LN(tgt+query_pos); qk = tgt+query_pos
    addln_kernel<<<g600, b256, 0, stream>>>(tgt, query_pos, n4g, n4b, ws + OFF_LN4, ws + OFF_QK);
    // 2-3. point1 MLP hidden layers
    gemm_small<1><<<gS, b256, 0, stream>>>(ws + OFF_LN4, p1_W0, p1_b0, ws + OFF_H1, 600, 256, 256, 0, 1.f);
    gemm_small<1><<<gS, b256, 0, stream>>>(ws + OFF_H1, p1_W1, p1_b1, ws + OFF_H2, 600, 256, 256, 0, 1.f);
    // 4. tiny heads + ref/point/scale2 assembly (writes d_out ref_inter + ref)
    small_heads<<<g600, dim3(64), 0, stream>>>(ws + OFF_LN4, ws + OFF_H2, p2W, p2b, p3W, p3b,
                                               p1_W2, p1_b2, h_w,
                                               out + 153600, out + 154800,
                                               ws + OFF_POINT, ws + OFF_SCALE2);
    // 5-7. self-attention projections (head layout [bh][300][32])
    gemm_small<2><<<gS, b256, 0, stream>>>(ws + OFF_QK, sa_Wi,          sa_bi,       ws + OFF_SAQ, 600, 256, 256, 300, qscale);
    gemm_small<2><<<gS, b256, 0, stream>>>(ws + OFF_QK, sa_Wi + 65536,  sa_bi + 256, ws + OFF_SAK, 600, 256, 256, 300, 1.f);
    gemm_small<2><<<gS, b256, 0, stream>>>(tgt,         sa_Wi + 131072, sa_bi + 512, ws + OFF_SAV, 600, 256, 256, 300, 1.f);
    // 8. self-attention: split over S into 2 chunks (5 tiles -> 3+2)
    attn_split<false><<<dim3(19, 16, 2), b256, 0, stream>>>(
        ws + OFF_SAQ, ws + OFF_SAK, ws + OFF_SAV, nullptr, nullptr, nullptr,
        ws + OFF_PACC, ws + OFF_PM, ws + OFF_PL, 300, 300, 3, 304);
    attn_combine<<<g600, b256, 0, stream>>>(ws + OFF_PACC, ws + OFF_PM, ws + OFF_PL,
                                            ws + OFF_AOUT, 2, 304, 300);
    // 9-10. SA out proj + LN1
    gemm_small<0><<<gS, b256, 0, stream>>>(ws + OFF_AOUT, sa_Wo, sa_bo, ws + OFF_TMP, 600, 256, 256, 0, 1.f);
    addln_kernel<<<g600, b256, 0, stream>>>(tgt, ws + OFF_TMP, n1g, n1b, ws + OFF_X1, nullptr);
    // 11. mp = memory + pos
    addvec_kernel<<<dim3(2048), b256, 0, stream>>>(memory, pos, ws + OFF_MP, (SN * BN * DN) / 4);
    // 12-13. CA K/V projections (shared by both passes), head layout [bh][4096][32]
    gemm_nt<2><<<gKV, b256, 0, stream>>>(ws + OFF_MP, ca_Wi + 65536,  ca_bi + 256, ws + OFF_CAK, 8192, 256, 256, 4096, 1.f);
    gemm_nt<2><<<gKV, b256, 0, stream>>>(memory,      ca_Wi + 131072, ca_bi + 512, ws + OFF_CAV, 8192, 256, 256, 4096, 1.f);
    // 14. xq = x1+query_pos ; xo = x1+new_oq
    build_xq_xo<<<g600, b256, 0, stream>>>(ws + OFF_X1, query_pos, ro1, ro2, ws + OFF_XQ, ws + OFF_XO);
    // 15-16. CA Q projections
    gemm_small<2><<<gS, b256, 0, stream>>>(ws + OFF_XQ, ca_Wi, ca_bi, ws + OFF_SAQ, 600, 256, 256, 300, qscale);
    gemm_small<2><<<gS, b256, 0, stream>>>(ws + OFF_XO, ca_Wi, ca_bi, ws + OFF_SAK, 600, 256, 256, 300, qscale);
    // 17. cross attention #1: split S=4096 into 8 chunks of 8 tiles
    attn_split<true><<<dim3(19, 16, 8), b256, 0, stream>>>(
        ws + OFF_SAQ, ws + OFF_CAK, ws + OFF_CAV,
        ws + OFF_POINT, ws + OFF_SCALE2, grid_in,
        ws + OFF_PACC, ws + OFF_PM, ws + OFF_PL, 4096, 300, 8, 304);
    attn_combine<<<g600, b256, 0, stream>>>(ws + OFF_PACC, ws + OFF_PM, ws + OFF_PL,
                                            ws + OFF_AOUT2, 8, 304, 300);
    // 18. cross attention #2
    attn_split<true><<<dim3(19, 16, 8), b256, 0, stream>>>(
        ws + OFF_SAK, ws + OFF_CAK, ws + OFF_CAV,
        ws + OFF_POINT, ws + OFF_SCALE2, grid_in,
        ws + OFF_PACC, ws + OFF_PM, ws + OFF_PL, 4096, 300, 8, 304);
    attn_combine<<<g600, b256, 0, stream>>>(ws + OFF_PACC, ws + OFF_PM, ws + OFF_PL,
                                            ws + OFF_AOUT3, 8, 304, 300);
    // 19-20. CA out projections (tgt3 straight to d_out)
    gemm_small<0><<<gS, b256, 0, stream>>>(ws + OFF_AOUT2, ca_Wo, ca_bo, ws + OFF_TMP, 600, 256, 256, 0, 1.f);
    gemm_small<0><<<gS, b256, 0, stream>>>(ws + OFF_AOUT3, ca_Wo, ca_bo, out + 164400, 600, 256, 256, 0, 1.f);
    // 21. LN2
    addln_kernel<<<g600, b256, 0, stream>>>(ws + OFF_X1, ws + OFF_TMP, n2g, n2b, ws + OFF_X2, nullptr);
    // 22-23. FFN
    gemm_small<1><<<gFF1, b256, 0, stream>>>(ws + OFF_X2, W1, b1, ws + OFF_FFH, 600, 2048, 256, 0, 1.f);
    gemm_small<0><<<gS, b256, 0, stream>>>(ws + OFF_FFH, W2, b2, ws + OFF_TMP, 600, 256, 2048, 0, 1.f);
    // 24. LN3 -> x output
    addln_kernel<<<g600, b256, 0, stream>>>(ws + OFF_X2, ws + OFF_TMP, n3g, n3b, out, nullptr);
}